// Round 4
// baseline (294.305 us; speedup 1.0000x reference)
//
#include <hip/hip_runtime.h>

// GIN 2-layer forward, f32 — CSR via two-level counting sort (no hot global atomics).
// Pipeline:
//   bin_hist -> scan_bins -> partition (pack (src<<8)|dstLocal per bin) -> bin_finalize
//   agg1 = x + gather(x)            [gather64]
//   h    = relu(agg1 @ W1 + b1)     [gemm1_relu]
//   g    = h @ W2                   [gemm2]
//   out  = g + b2 + gather(g)       [gather64 with bias]
// (W2 folded before aggregation-2: (A h + h) W2 + b2 = A(hW2) + hW2 + b2.)

#define EPB 4096     // edges per block in bin_hist / partition
#define CAP 6144     // LDS staging cap for bin_finalize (bins avg ~4092 edges)

// per-block LDS histogram of dst>>8, flushed with one global atomic per bin
__global__ __launch_bounds__(256) void bin_hist(const int* __restrict__ dst,
                                                int* __restrict__ binCnt, int ne, int nbins) {
    __shared__ int h[512];
    int t = threadIdx.x;
    for (int i = t; i < nbins; i += 256) h[i] = 0;
    __syncthreads();
    int eb = blockIdx.x * EPB;
#pragma unroll
    for (int i = 0; i < 16; ++i) {
        int e = eb + t + i * 256;
        if (e < ne) atomicAdd(&h[dst[e] >> 8], 1);
    }
    __syncthreads();
    for (int i = t; i < nbins; i += 256) if (h[i]) atomicAdd(&binCnt[i], h[i]);
}

// single-block exclusive scan of binCnt (nbins <= 512)
__global__ __launch_bounds__(512) void scan_bins(const int* __restrict__ binCnt,
                                                 int* __restrict__ binOff, int* __restrict__ binCur,
                                                 int* __restrict__ off, int nbins, int n, int ne) {
    __shared__ int s[512];
    int t = threadIdx.x;
    int v = (t < nbins) ? binCnt[t] : 0;
    s[t] = v;
    __syncthreads();
    for (int o = 1; o < 512; o <<= 1) {
        int u = (t >= o) ? s[t - o] : 0;
        __syncthreads();
        s[t] += u;
        __syncthreads();
    }
    if (t < nbins) { int b = s[t] - v; binOff[t] = b; binCur[t] = b; }
    if (t == 0) { binOff[nbins] = ne; off[n] = ne; }
}

// scatter edges into bin regions; entry = (src<<8) | (dst & 255)
__global__ __launch_bounds__(256) void partition(const int* __restrict__ src,
                                                 const int* __restrict__ dst,
                                                 int* __restrict__ binCur,
                                                 unsigned* __restrict__ part, int ne, int nbins) {
    __shared__ int h[512];
    __shared__ int base[512];
    int t = threadIdx.x;
    for (int i = t; i < nbins; i += 256) h[i] = 0;
    __syncthreads();
    int eb = blockIdx.x * EPB;
    int ss[16], ds[16];
#pragma unroll
    for (int i = 0; i < 16; ++i) {
        int e = eb + t + i * 256;
        if (e < ne) { ss[i] = src[e]; ds[i] = dst[e]; atomicAdd(&h[ds[i] >> 8], 1); }
        else ds[i] = -1;
    }
    __syncthreads();
    for (int i = t; i < nbins; i += 256) base[i] = h[i] ? atomicAdd(&binCur[i], h[i]) : 0;
    __syncthreads();
    for (int i = t; i < nbins; i += 256) h[i] = 0;   // reuse as local cursor
    __syncthreads();
#pragma unroll
    for (int i = 0; i < 16; ++i) {
        if (ds[i] >= 0) {
            int b = ds[i] >> 8;
            int p = atomicAdd(&h[b], 1);
            part[base[b] + p] = ((unsigned)ss[i] << 8) | (unsigned)(ds[i] & 255);
        }
    }
}

// one block per bin: LDS-stage its edges, local hist+scan, emit perm[] and off[]
__global__ __launch_bounds__(256) void bin_finalize(const unsigned* __restrict__ part,
                                                    const int* __restrict__ binOff,
                                                    int* __restrict__ off, int* __restrict__ perm,
                                                    int n, int nbins) {
    __shared__ unsigned st[CAP];
    __shared__ int cnt[256], ex[256], cur[256];
    int b = blockIdx.x;
    int t = threadIdx.x;
    int e0 = binOff[b], e1 = binOff[b + 1];
    int m = e1 - e0;
    int nb0 = b << 8;
    int nn = min(256, n - nb0);
    cnt[t] = 0;
    __syncthreads();
    bool staged = (m <= CAP);
    if (staged) {
        for (int i = t; i < m; i += 256) { unsigned v = part[e0 + i]; st[i] = v; atomicAdd(&cnt[v & 255u], 1); }
    } else {
        for (int i = t; i < m; i += 256) { unsigned v = part[e0 + i]; atomicAdd(&cnt[v & 255u], 1); }
    }
    __syncthreads();
    int v = cnt[t];
    ex[t] = v;
    __syncthreads();
    for (int o = 1; o < 256; o <<= 1) {
        int u = (t >= o) ? ex[t - o] : 0;
        __syncthreads();
        ex[t] += u;
        __syncthreads();
    }
    int excl = ex[t] - v;
    if (t < nn) off[nb0 + t] = e0 + excl;
    cur[t] = excl;
    __syncthreads();
    if (staged) {
        for (int i = t; i < m; i += 256) {
            unsigned w = st[i];
            int p = atomicAdd(&cur[w & 255u], 1);
            perm[e0 + p] = (int)(w >> 8);
        }
    } else {
        for (int i = t; i < m; i += 256) {
            unsigned w = part[e0 + i];
            int p = atomicAdd(&cur[w & 255u], 1);
            perm[e0 + p] = (int)(w >> 8);
        }
    }
}

// out[i] = x[i] + sum_{e in CSR(i)} x[perm[e]]  (+ bias if given)
__global__ __launch_bounds__(256) void gather64(const float4* __restrict__ x4,
                                                const int* __restrict__ off,
                                                const int* __restrict__ perm,
                                                const float* __restrict__ bias,
                                                float4* __restrict__ out4, int n) {
    int t = threadIdx.x;
    int node = blockIdx.x * 16 + (t >> 4);
    int c = t & 15;
    if (node >= n) return;
    int beg = off[node], end = off[node + 1];
    float4 acc = x4[(size_t)node * 16 + c];
    for (int e = beg; e < end; ++e) {
        int s = perm[e];
        float4 v = x4[(size_t)s * 16 + c];
        acc.x += v.x; acc.y += v.y; acc.z += v.z; acc.w += v.w;
    }
    if (bias) {
        float4 bb = reinterpret_cast<const float4*>(bias)[c];
        acc.x += bb.x; acc.y += bb.y; acc.z += bb.z; acc.w += bb.w;
    }
    out4[(size_t)node * 16 + c] = acc;
}

// h[n,128] = relu(x[n,64] @ W1[64,128] + b1); 8 rows/block
__global__ __launch_bounds__(256) void gemm1_relu(const float* __restrict__ x,
                                                  const float* __restrict__ W1,
                                                  const float* __restrict__ b1,
                                                  float* __restrict__ h, int n) {
    __shared__ float4 Ws[64][32];
    __shared__ float  xs[8][64];
    int t = threadIdx.x;
    const float4* W4 = reinterpret_cast<const float4*>(W1);
    for (int i = t; i < 64 * 32; i += 256) Ws[i >> 5][i & 31] = W4[i];
    int row0 = blockIdx.x * 8;
    const float4* x4 = reinterpret_cast<const float4*>(x + (size_t)row0 * 64);
    float4* xs4 = reinterpret_cast<float4*>(&xs[0][0]);
    if (t < 128) xs4[t] = x4[t];
    __syncthreads();

    int row = t >> 5;
    int cg  = t & 31;
    float4 acc = {0.f, 0.f, 0.f, 0.f};
#pragma unroll
    for (int k = 0; k < 64; ++k) {
        float a = xs[row][k];
        float4 w = Ws[k][cg];
        acc.x += a * w.x; acc.y += a * w.y; acc.z += a * w.z; acc.w += a * w.w;
    }
    float4 b = reinterpret_cast<const float4*>(b1)[cg];
    acc.x = fmaxf(acc.x + b.x, 0.f);
    acc.y = fmaxf(acc.y + b.y, 0.f);
    acc.z = fmaxf(acc.z + b.z, 0.f);
    acc.w = fmaxf(acc.w + b.w, 0.f);
    reinterpret_cast<float4*>(h + (size_t)(row0 + row) * 128)[cg] = acc;
}

// g[n,64] = h[n,128] @ W2[128,64]; 16 rows/block
__global__ __launch_bounds__(256) void gemm2(const float* __restrict__ h,
                                             const float* __restrict__ W2,
                                             float* __restrict__ g, int n) {
    __shared__ float4 Ws[128][16];
    __shared__ float  xs[16][132];
    int t = threadIdx.x;
    const float4* W4 = reinterpret_cast<const float4*>(W2);
    for (int i = t; i < 128 * 16; i += 256) Ws[i >> 4][i & 15] = W4[i];
    int row0 = blockIdx.x * 16;
    const float4* x4 = reinterpret_cast<const float4*>(h + (size_t)row0 * 128);
    for (int i = t; i < 512; i += 256) {
        int r = i >> 5, c = i & 31;
        *reinterpret_cast<float4*>(&xs[r][c * 4]) = x4[i];
    }
    __syncthreads();

    int row = t >> 4;
    int cg  = t & 15;
    float4 acc = {0.f, 0.f, 0.f, 0.f};
#pragma unroll
    for (int k = 0; k < 128; ++k) {
        float a = xs[row][k];
        float4 w = Ws[k][cg];
        acc.x += a * w.x; acc.y += a * w.y; acc.z += a * w.z; acc.w += a * w.w;
    }
    reinterpret_cast<float4*>(g)[(size_t)(row0 + row) * 16 + cg] = acc;
}

extern "C" void kernel_launch(void* const* d_in, const int* in_sizes, int n_in,
                              void* d_out, int out_size, void* d_ws, size_t ws_size,
                              hipStream_t stream) {
    const float* node_emb = (const float*)d_in[0];
    const float* W1 = (const float*)d_in[1];
    const float* b1 = (const float*)d_in[2];
    const float* W2 = (const float*)d_in[3];
    const float* b2 = (const float*)d_in[4];
    const int*   ei = (const int*)d_in[5];
    int n  = in_sizes[0] / 64;
    int ne = in_sizes[5] / 2;
    const int* src = ei;
    const int* dst = ei + ne;
    float* out = (float*)d_out;

    int nbins = (n + 255) >> 8;   // 391

    // workspace layout (part aliases h: part is dead before gemm1 writes h)
    char* ws = (char*)d_ws;
    float* agg1 = (float*)ws;                                  // n*64 f32, reused as g
    float* h    = (float*)(ws + (size_t)n * 64 * 4);           // n*128 f32
    unsigned* part = (unsigned*)h;                             // ne u32 (alias, dead by gemm1)
    char*  p    = ws + (size_t)n * 64 * 4 + (size_t)n * 128 * 4;
    int* off    = (int*)p;            p += (size_t)(n + 1) * 4;
    int* perm   = (int*)p;            p += (size_t)ne * 4;
    int* binCnt = (int*)p;            p += (size_t)(nbins + 1) * 4;
    int* binOff = (int*)p;            p += (size_t)(nbins + 1) * 4;
    int* binCur = (int*)p;            p += (size_t)(nbins + 1) * 4;
    float* g = agg1;                                           // agg1 dead after gemm1

    int nblk = (ne + EPB - 1) / EPB;   // 391

    hipMemsetAsync(binCnt, 0, (size_t)nbins * 4, stream);
    bin_hist<<<nblk, 256, 0, stream>>>(dst, binCnt, ne, nbins);
    scan_bins<<<1, 512, 0, stream>>>(binCnt, binOff, binCur, off, nbins, n, ne);
    partition<<<nblk, 256, 0, stream>>>(src, dst, binCur, part, ne, nbins);
    bin_finalize<<<nbins, 256, 0, stream>>>(part, binOff, off, perm, n, nbins);

    gather64<<<(n + 15) / 16, 256, 0, stream>>>((const float4*)node_emb, off, perm,
                                                nullptr, (float4*)agg1, n);
    gemm1_relu<<<(n + 7) / 8, 256, 0, stream>>>(agg1, W1, b1, h, n);
    gemm2<<<(n + 15) / 16, 256, 0, stream>>>(h, W2, g, n);
    gather64<<<(n + 15) / 16, 256, 0, stream>>>((const float4*)g, off, perm,
                                                b2, (float4*)out, n);
}

// Round 5
// 256.547 us; speedup vs baseline: 1.1472x; 1.1472x over previous
//
#include <hip/hip_runtime.h>

// GIN 2-layer forward, f32 — CSR two-level counting sort + MLP-batched gathers.
// Pipeline:
//   bin_hist -> scan_bins -> partition -> bin_finalize        (CSR by dst)
//   h   = relu((x + gather(x)) @ W1 + b1)    [fused_agg_gemm1: gather->LDS->GEMM]
//   g   = h @ W2                             [gemm2]
//   out = g + b2 + gather(g)                 [gather64, 4-deep batched]
// (W2 folded before aggregation-2: (A h + h) W2 + b2 = A(hW2) + hW2 + b2.)

#define EPB 4096     // edges per block in bin_hist / partition
#define CAP 6144     // LDS staging cap for bin_finalize

__global__ __launch_bounds__(256) void bin_hist(const int* __restrict__ dst,
                                                int* __restrict__ binCnt, int ne, int nbins) {
    __shared__ int h[512];
    int t = threadIdx.x;
    for (int i = t; i < nbins; i += 256) h[i] = 0;
    __syncthreads();
    int eb = blockIdx.x * EPB;
#pragma unroll
    for (int i = 0; i < 16; ++i) {
        int e = eb + t + i * 256;
        if (e < ne) atomicAdd(&h[dst[e] >> 8], 1);
    }
    __syncthreads();
    for (int i = t; i < nbins; i += 256) if (h[i]) atomicAdd(&binCnt[i], h[i]);
}

__global__ __launch_bounds__(512) void scan_bins(const int* __restrict__ binCnt,
                                                 int* __restrict__ binOff, int* __restrict__ binCur,
                                                 int* __restrict__ off, int nbins, int n, int ne) {
    __shared__ int s[512];
    int t = threadIdx.x;
    int v = (t < nbins) ? binCnt[t] : 0;
    s[t] = v;
    __syncthreads();
    for (int o = 1; o < 512; o <<= 1) {
        int u = (t >= o) ? s[t - o] : 0;
        __syncthreads();
        s[t] += u;
        __syncthreads();
    }
    if (t < nbins) { int b = s[t] - v; binOff[t] = b; binCur[t] = b; }
    if (t == 0) { binOff[nbins] = ne; off[n] = ne; }
}

__global__ __launch_bounds__(256) void partition(const int* __restrict__ src,
                                                 const int* __restrict__ dst,
                                                 int* __restrict__ binCur,
                                                 unsigned* __restrict__ part, int ne, int nbins) {
    __shared__ int h[512];
    __shared__ int base[512];
    int t = threadIdx.x;
    for (int i = t; i < nbins; i += 256) h[i] = 0;
    __syncthreads();
    int eb = blockIdx.x * EPB;
    int ss[16], ds[16];
#pragma unroll
    for (int i = 0; i < 16; ++i) {
        int e = eb + t + i * 256;
        if (e < ne) { ss[i] = src[e]; ds[i] = dst[e]; atomicAdd(&h[ds[i] >> 8], 1); }
        else ds[i] = -1;
    }
    __syncthreads();
    for (int i = t; i < nbins; i += 256) base[i] = h[i] ? atomicAdd(&binCur[i], h[i]) : 0;
    __syncthreads();
    for (int i = t; i < nbins; i += 256) h[i] = 0;
    __syncthreads();
#pragma unroll
    for (int i = 0; i < 16; ++i) {
        if (ds[i] >= 0) {
            int b = ds[i] >> 8;
            int p = atomicAdd(&h[b], 1);
            part[base[b] + p] = ((unsigned)ss[i] << 8) | (unsigned)(ds[i] & 255);
        }
    }
}

__global__ __launch_bounds__(256) void bin_finalize(const unsigned* __restrict__ part,
                                                    const int* __restrict__ binOff,
                                                    int* __restrict__ off, int* __restrict__ perm,
                                                    int n, int nbins) {
    __shared__ unsigned st[CAP];
    __shared__ int cnt[256], ex[256], cur[256];
    int b = blockIdx.x;
    int t = threadIdx.x;
    int e0 = binOff[b], e1 = binOff[b + 1];
    int m = e1 - e0;
    int nb0 = b << 8;
    int nn = min(256, n - nb0);
    cnt[t] = 0;
    __syncthreads();
    bool staged = (m <= CAP);
    if (staged) {
        for (int i = t; i < m; i += 256) { unsigned v = part[e0 + i]; st[i] = v; atomicAdd(&cnt[v & 255u], 1); }
    } else {
        for (int i = t; i < m; i += 256) { unsigned v = part[e0 + i]; atomicAdd(&cnt[v & 255u], 1); }
    }
    __syncthreads();
    int v = cnt[t];
    ex[t] = v;
    __syncthreads();
    for (int o = 1; o < 256; o <<= 1) {
        int u = (t >= o) ? ex[t - o] : 0;
        __syncthreads();
        ex[t] += u;
        __syncthreads();
    }
    int excl = ex[t] - v;
    if (t < nn) off[nb0 + t] = e0 + excl;
    cur[t] = excl;
    __syncthreads();
    if (staged) {
        for (int i = t; i < m; i += 256) {
            unsigned w = st[i];
            int p = atomicAdd(&cur[w & 255u], 1);
            perm[e0 + p] = (int)(w >> 8);
        }
    } else {
        for (int i = t; i < m; i += 256) {
            unsigned w = part[e0 + i];
            int p = atomicAdd(&cur[w & 255u], 1);
            perm[e0 + p] = (int)(w >> 8);
        }
    }
}

// layer 1 fused: per block, gather 16 nodes' aggregated rows into LDS, then
// GEMM 64->128 + bias + relu. Gather phase: 16 lanes/node, 4-deep edge batch.
__global__ __launch_bounds__(256) void fused_agg_gemm1(const float4* __restrict__ x4,
                                                       const int* __restrict__ off,
                                                       const int* __restrict__ perm,
                                                       const float* __restrict__ W1,
                                                       const float* __restrict__ b1,
                                                       float* __restrict__ h, int n) {
    __shared__ float4 Ws[64][32];   // 32 KiB
    __shared__ float  xs[16][68];   // 4.25 KiB, stride 68 keeps float4 alignment
    int t = threadIdx.x;
    const float4* W4 = reinterpret_cast<const float4*>(W1);
    for (int i = t; i < 64 * 32; i += 256) Ws[i >> 5][i & 31] = W4[i];

    int row0 = blockIdx.x * 16;
    int r = t >> 4;
    int c = t & 15;
    int node = row0 + r;
    if (node < n) {
        int beg = off[node], end = off[node + 1];
        float4 acc = x4[(size_t)node * 16 + c];
        int e = beg;
        for (; e + 4 <= end; e += 4) {
            int s0 = perm[e], s1 = perm[e + 1], s2 = perm[e + 2], s3 = perm[e + 3];
            float4 v0 = x4[(size_t)s0 * 16 + c];
            float4 v1 = x4[(size_t)s1 * 16 + c];
            float4 v2 = x4[(size_t)s2 * 16 + c];
            float4 v3 = x4[(size_t)s3 * 16 + c];
            acc.x += (v0.x + v1.x) + (v2.x + v3.x);
            acc.y += (v0.y + v1.y) + (v2.y + v3.y);
            acc.z += (v0.z + v1.z) + (v2.z + v3.z);
            acc.w += (v0.w + v1.w) + (v2.w + v3.w);
        }
        for (; e < end; ++e) {
            int s = perm[e];
            float4 v = x4[(size_t)s * 16 + c];
            acc.x += v.x; acc.y += v.y; acc.z += v.z; acc.w += v.w;
        }
        xs[r][c * 4 + 0] = acc.x;
        xs[r][c * 4 + 1] = acc.y;
        xs[r][c * 4 + 2] = acc.z;
        xs[r][c * 4 + 3] = acc.w;
    }
    __syncthreads();

    if (node >= n) return;
    float4 a0 = {0.f, 0.f, 0.f, 0.f}, a1 = {0.f, 0.f, 0.f, 0.f};
#pragma unroll
    for (int k = 0; k < 64; ++k) {
        float a = xs[r][k];
        float4 w0 = Ws[k][c];
        float4 w1 = Ws[k][c + 16];
        a0.x += a * w0.x; a0.y += a * w0.y; a0.z += a * w0.z; a0.w += a * w0.w;
        a1.x += a * w1.x; a1.y += a * w1.y; a1.z += a * w1.z; a1.w += a * w1.w;
    }
    const float4* b4 = reinterpret_cast<const float4*>(b1);
    float4 q0 = b4[c], q1 = b4[c + 16];
    a0.x = fmaxf(a0.x + q0.x, 0.f); a0.y = fmaxf(a0.y + q0.y, 0.f);
    a0.z = fmaxf(a0.z + q0.z, 0.f); a0.w = fmaxf(a0.w + q0.w, 0.f);
    a1.x = fmaxf(a1.x + q1.x, 0.f); a1.y = fmaxf(a1.y + q1.y, 0.f);
    a1.z = fmaxf(a1.z + q1.z, 0.f); a1.w = fmaxf(a1.w + q1.w, 0.f);
    float4* h4 = reinterpret_cast<float4*>(h) + (size_t)node * 32;
    h4[c] = a0;
    h4[c + 16] = a1;
}

// g[n,64] = h[n,128] @ W2[128,64]; 16 rows/block
__global__ __launch_bounds__(256) void gemm2(const float* __restrict__ h,
                                             const float* __restrict__ W2,
                                             float* __restrict__ g, int n) {
    __shared__ float4 Ws[128][16];
    __shared__ float  xs[16][132];
    int t = threadIdx.x;
    const float4* W4 = reinterpret_cast<const float4*>(W2);
    for (int i = t; i < 128 * 16; i += 256) Ws[i >> 4][i & 15] = W4[i];
    int row0 = blockIdx.x * 16;
    const float4* x4 = reinterpret_cast<const float4*>(h + (size_t)row0 * 128);
    for (int i = t; i < 512; i += 256) {
        int r = i >> 5, c = i & 31;
        *reinterpret_cast<float4*>(&xs[r][c * 4]) = x4[i];
    }
    __syncthreads();

    int row = t >> 4;
    int cg  = t & 15;
    float4 acc = {0.f, 0.f, 0.f, 0.f};
#pragma unroll
    for (int k = 0; k < 128; ++k) {
        float a = xs[row][k];
        float4 w = Ws[k][cg];
        acc.x += a * w.x; acc.y += a * w.y; acc.z += a * w.z; acc.w += a * w.w;
    }
    reinterpret_cast<float4*>(g)[(size_t)(row0 + row) * 16 + cg] = acc;
}

// out[i] = x[i] + bias + sum_{e in CSR(i)} x[perm[e]]  (4-deep edge batch)
__global__ __launch_bounds__(256) void gather64(const float4* __restrict__ x4,
                                                const int* __restrict__ off,
                                                const int* __restrict__ perm,
                                                const float* __restrict__ bias,
                                                float4* __restrict__ out4, int n) {
    int t = threadIdx.x;
    int node = blockIdx.x * 16 + (t >> 4);
    int c = t & 15;
    if (node >= n) return;
    int beg = off[node], end = off[node + 1];
    float4 acc = x4[(size_t)node * 16 + c];
    int e = beg;
    for (; e + 4 <= end; e += 4) {
        int s0 = perm[e], s1 = perm[e + 1], s2 = perm[e + 2], s3 = perm[e + 3];
        float4 v0 = x4[(size_t)s0 * 16 + c];
        float4 v1 = x4[(size_t)s1 * 16 + c];
        float4 v2 = x4[(size_t)s2 * 16 + c];
        float4 v3 = x4[(size_t)s3 * 16 + c];
        acc.x += (v0.x + v1.x) + (v2.x + v3.x);
        acc.y += (v0.y + v1.y) + (v2.y + v3.y);
        acc.z += (v0.z + v1.z) + (v2.z + v3.z);
        acc.w += (v0.w + v1.w) + (v2.w + v3.w);
    }
    for (; e < end; ++e) {
        int s = perm[e];
        float4 v = x4[(size_t)s * 16 + c];
        acc.x += v.x; acc.y += v.y; acc.z += v.z; acc.w += v.w;
    }
    float4 bb = reinterpret_cast<const float4*>(bias)[c];
    acc.x += bb.x; acc.y += bb.y; acc.z += bb.z; acc.w += bb.w;
    out4[(size_t)node * 16 + c] = acc;
}

extern "C" void kernel_launch(void* const* d_in, const int* in_sizes, int n_in,
                              void* d_out, int out_size, void* d_ws, size_t ws_size,
                              hipStream_t stream) {
    const float* node_emb = (const float*)d_in[0];
    const float* W1 = (const float*)d_in[1];
    const float* b1 = (const float*)d_in[2];
    const float* W2 = (const float*)d_in[3];
    const float* b2 = (const float*)d_in[4];
    const int*   ei = (const int*)d_in[5];
    int n  = in_sizes[0] / 64;
    int ne = in_sizes[5] / 2;
    const int* src = ei;
    const int* dst = ei + ne;
    float* out = (float*)d_out;

    int nbins = (n + 255) >> 8;   // 391

    // workspace layout (part aliases h: part is dead before fused1 writes h)
    char* ws = (char*)d_ws;
    float* g    = (float*)ws;                                  // n*64 f32
    float* h    = (float*)(ws + (size_t)n * 64 * 4);           // n*128 f32
    unsigned* part = (unsigned*)h;                             // ne u32 (alias, dead by fused1)
    char*  p    = ws + (size_t)n * 64 * 4 + (size_t)n * 128 * 4;
    int* off    = (int*)p;            p += (size_t)(n + 1) * 4;
    int* perm   = (int*)p;            p += (size_t)ne * 4;
    int* binCnt = (int*)p;            p += (size_t)(nbins + 1) * 4;
    int* binOff = (int*)p;            p += (size_t)(nbins + 1) * 4;
    int* binCur = (int*)p;            p += (size_t)(nbins + 1) * 4;

    int nblk = (ne + EPB - 1) / EPB;   // 391

    hipMemsetAsync(binCnt, 0, (size_t)nbins * 4, stream);
    bin_hist<<<nblk, 256, 0, stream>>>(dst, binCnt, ne, nbins);
    scan_bins<<<1, 512, 0, stream>>>(binCnt, binOff, binCur, off, nbins, n, ne);
    partition<<<nblk, 256, 0, stream>>>(src, dst, binCur, part, ne, nbins);
    bin_finalize<<<nbins, 256, 0, stream>>>(part, binOff, off, perm, n, nbins);

    fused_agg_gemm1<<<(n + 15) / 16, 256, 0, stream>>>((const float4*)node_emb, off, perm,
                                                       W1, b1, h, n);
    gemm2<<<(n + 15) / 16, 256, 0, stream>>>(h, W2, g, n);
    gather64<<<(n + 15) / 16, 256, 0, stream>>>((const float4*)g, off, perm,
                                                b2, (float4*)out, n);
}